// Round 1
// baseline (557.059 us; speedup 1.0000x reference)
//
#include <hip/hip_runtime.h>

// Problem constants (from reference): b=4, c=64, h=w=128, ks=3, N=9,
// offset channels = 18, out channels = 64, padded Hp=Wp=130.
#define BATCH 4
#define CH    64
#define HH    128
#define WW    128
#define HW    (HH*WW)          // 16384
#define NOFF  18               // 2*N
#define KTOT  576              // CH*9
#define OC    64

// ---------------------------------------------------------------------------
// Kernel 1: offset = conv2d(x1, p_w, p_b, stride=1, pad=1)  -> (4,18,128,128)
// One block per (b, 16x16 pixel tile). Loop over input channels, staging an
// 18x18 x1 tile in LDS; weights are thread-uniform -> scalar loads.
// ---------------------------------------------------------------------------
__global__ __launch_bounds__(256) void offset_conv(
    const float* __restrict__ x1, const float* __restrict__ pw,
    const float* __restrict__ pb, float* __restrict__ offset) {
  __shared__ float tile[18][20];   // +2 pad: max 2-way bank aliasing (free)
  int blk = blockIdx.x;            // b*64 + ti*8 + tj
  int b  = blk >> 6;
  int ti = (blk >> 3) & 7;
  int tj = blk & 7;
  int i0 = ti * 16, j0 = tj * 16;
  int tx = threadIdx.x & 15, ty = threadIdx.x >> 4;

  float acc[NOFF];
#pragma unroll
  for (int o = 0; o < NOFF; o++) acc[o] = pb[o];

  for (int c = 0; c < CH; c++) {
    const float* src = x1 + (b * CH + c) * HW;
    for (int e = threadIdx.x; e < 18 * 18; e += 256) {
      int r = e / 18, q = e % 18;
      int gi = i0 + r - 1, gj = j0 + q - 1;
      float v = 0.f;
      if ((unsigned)gi < 128u && (unsigned)gj < 128u) v = src[gi * WW + gj];
      tile[r][q] = v;
    }
    __syncthreads();
    float v[9];
#pragma unroll
    for (int di = 0; di < 3; di++)
#pragma unroll
      for (int dj = 0; dj < 3; dj++) v[di * 3 + dj] = tile[ty + di][tx + dj];
    const float* wc = pw + c * 9;   // pw[(o*64 + c)*9 + d]
#pragma unroll
    for (int o = 0; o < NOFF; o++) {
      const float* w9 = wc + o * (CH * 9);
#pragma unroll
      for (int d = 0; d < 9; d++) acc[o] += w9[d] * v[d];
    }
    __syncthreads();
  }
  int i = i0 + ty, j = j0 + tx;
#pragma unroll
  for (int o = 0; o < NOFF; o++)
    offset[((b * NOFF + o) * HH + i) * WW + j] = acc[o];
}

// ---------------------------------------------------------------------------
// Kernel 2: wT[t][oc] = conv_w[oc][t]   (t = c*9 + k), 576x64
// ---------------------------------------------------------------------------
__global__ void transpose_w(const float* __restrict__ cw, float* __restrict__ wT) {
  int idx = blockIdx.x * 256 + threadIdx.x;   // 144*256 == 64*576 exactly
  int oc = idx / KTOT, t = idx % KTOT;
  wT[t * OC + oc] = cw[idx];
}

// ---------------------------------------------------------------------------
// Kernel 3: fused bilinear deform gather + final conv (tall-skinny GEMM).
// One block per (b, i, 16-wide j strip). Phase B: gather xoff[16][576] into
// LDS (stride 577 -> conflict-free column reads). Phase C: each thread does
// 1 pixel x 4 oc, K=576, with coalesced float4 wT loads (L2-hot).
// ---------------------------------------------------------------------------
__global__ __launch_bounds__(256) void deform_gemm(
    const float* __restrict__ x0, const float* __restrict__ offset,
    const float* __restrict__ wT, float* __restrict__ out) {
  __shared__ float xoff[16 * 577];   // 36928 B

  int blk = blockIdx.x;              // b*1024 + i*8 + jt
  int b  = blk >> 10;
  int i  = (blk >> 3) & 127;
  int j0 = (blk & 7) << 4;
  int tid = threadIdx.x;

  // ---- Phase B: bilinear gather into LDS ----
  {
    int pix = tid & 15;
    int tg  = tid >> 4;      // 0..15 -> 4 channels each
    int c0  = tg * 4;
    int j   = j0 + pix;
    const float* xb = x0 + b * CH * HW;
    const float* offp = offset + (b * NOFF * HH + i) * WW + j;
#pragma unroll 1
    for (int k = 0; k < 9; k++) {
      float ox = offp[k * HW];
      float oy = offp[(k + 9) * HW];
      // p = p0 + p_n + offset;  p0x=i+1, pnx=k/3-1  ->  i + k/3 + ox
      float pxr = (float)(i + k / 3) + ox;
      float pyr = (float)(j + k % 3) + oy;
      float fx = floorf(pxr), fy = floorf(pyr);
      float qltx = fminf(fmaxf(fx, 0.f), 129.f);
      float qlty = fminf(fmaxf(fy, 0.f), 129.f);
      float qrbx = fminf(fmaxf(fx + 1.f, 0.f), 129.f);
      float qrby = fminf(fmaxf(fy + 1.f, 0.f), 129.f);
      float px = fminf(fmaxf(pxr, 0.f), 129.f);
      float py = fminf(fmaxf(pyr, 0.f), 129.f);
      float glt = (1.f + qltx - px) * (1.f + qlty - py);
      float grb = (1.f - qrbx + px) * (1.f - qrby + py);
      float glb = (1.f + qltx - px) * (1.f - qrby + py);
      float grt = (1.f - qrbx + px) * (1.f + qlty - py);
      // padded coords -> unpadded x0 coords with validity (pad value 0)
      int ltx = (int)qltx - 1, lty = (int)qlty - 1;
      int rbx = (int)qrbx - 1, rby = (int)qrby - 1;
      bool vlx = (unsigned)ltx < 128u, vly = (unsigned)lty < 128u;
      bool vrx = (unsigned)rbx < 128u, vry = (unsigned)rby < 128u;
      int o_lt = ltx * WW + lty, o_rb = rbx * WW + rby;
      int o_lb = ltx * WW + rby, o_rt = rbx * WW + lty;
#pragma unroll
      for (int cc = 0; cc < 4; cc++) {
        const float* xc = xb + (c0 + cc) * HW;
        float vlt = (vlx && vly) ? xc[o_lt] : 0.f;
        float vrb = (vrx && vry) ? xc[o_rb] : 0.f;
        float vlb = (vlx && vry) ? xc[o_lb] : 0.f;
        float vrt = (vrx && vly) ? xc[o_rt] : 0.f;
        xoff[pix * 577 + (c0 + cc) * 9 + k] =
            glt * vlt + grb * vrb + glb * vlb + grt * vrt;
      }
    }
  }
  __syncthreads();

  // ---- Phase C: out[pix][oc] = sum_t xoff[pix][t] * wT[t][oc] ----
  {
    int pix = tid & 15;
    int ocg = tid >> 4;        // 16 groups x 4 oc
    int oc0 = ocg * 4;
    float a0 = 0.f, a1 = 0.f, a2 = 0.f, a3 = 0.f;
    const float* xrow = &xoff[pix * 577];
    const float* wp = wT + oc0;
#pragma unroll 4
    for (int t = 0; t < KTOT; t++) {
      float xv = xrow[t];
      float4 wv = *(const float4*)(wp + t * OC);
      a0 += xv * wv.x; a1 += xv * wv.y; a2 += xv * wv.z; a3 += xv * wv.w;
    }
    int j = j0 + pix;
    float* op = out + ((b * OC + oc0) * HH + i) * WW + j;
    op[0]          = a0;
    op[HW]         = a1;
    op[2 * HW]     = a2;
    op[3 * HW]     = a3;
  }
}

// ---------------------------------------------------------------------------
extern "C" void kernel_launch(void* const* d_in, const int* in_sizes, int n_in,
                              void* d_out, int out_size, void* d_ws, size_t ws_size,
                              hipStream_t stream) {
  const float* x0 = (const float*)d_in[0];
  const float* x1 = (const float*)d_in[1];
  const float* pw = (const float*)d_in[2];
  const float* pb = (const float*)d_in[3];
  const float* cw = (const float*)d_in[4];
  float* out = (float*)d_out;

  float* offset = (float*)d_ws;                          // 4*18*128*128 f32 = 4718592 B
  float* wT = (float*)((char*)d_ws + 4718592);           // 576*64 f32 = 147456 B

  offset_conv<<<dim3(BATCH * 64), dim3(256), 0, stream>>>(x1, pw, pb, offset);
  transpose_w<<<dim3(144), dim3(256), 0, stream>>>(cw, wT);
  deform_gemm<<<dim3(BATCH * 1024), dim3(256), 0, stream>>>(x0, offset, wT, out);
}

// Round 2
// 308.087 us; speedup vs baseline: 1.8081x; 1.8081x over previous
//
#include <hip/hip_runtime.h>

// Problem constants: b=4, c=64, h=w=128, ks=3, N=9, offset ch=18, oc=64.
#define BATCH 4
#define CH    64
#define HH    128
#define WW    128
#define HW    (HH*WW)          // 16384
#define NOFF  18               // 2*N
#define KTOT  576              // 9*CH (k-major: t = k*64 + c)
#define OC    64
#define PIX   32               // pixels per deform block
#define XS    584              // LDS row stride in bf16 (576 + 8, 16B aligned)

typedef __attribute__((ext_vector_type(8))) __bf16 bf16x8;
typedef __attribute__((ext_vector_type(4))) float f32x4;

// ---------------------------------------------------------------------------
// Kernel 1: offset = conv2d(x1, p_w, p_b, 1, 1) -> (4,18,128,128), f32.
// One block per (b, 16x16 tile); stage 4 input channels per barrier.
// ---------------------------------------------------------------------------
__global__ __launch_bounds__(256) void offset_conv(
    const float* __restrict__ x1, const float* __restrict__ pw,
    const float* __restrict__ pb, float* __restrict__ offset) {
  __shared__ float tile[4][18][20];
  int blk = blockIdx.x;            // b*64 + ti*8 + tj
  int b  = blk >> 6;
  int ti = (blk >> 3) & 7;
  int tj = blk & 7;
  int i0 = ti * 16, j0 = tj * 16;
  int tx = threadIdx.x & 15, ty = threadIdx.x >> 4;

  float acc[NOFF];
#pragma unroll
  for (int o = 0; o < NOFF; o++) acc[o] = pb[o];

  for (int c0 = 0; c0 < CH; c0 += 4) {
    for (int e = threadIdx.x; e < 4 * 18 * 18; e += 256) {
      int ch = e / 324, rem = e - ch * 324;
      int r = rem / 18, q = rem - r * 18;
      int gi = i0 + r - 1, gj = j0 + q - 1;
      float v = 0.f;
      if ((unsigned)gi < 128u && (unsigned)gj < 128u)
        v = x1[(b * CH + c0 + ch) * HW + gi * WW + gj];
      tile[ch][r][q] = v;
    }
    __syncthreads();
#pragma unroll
    for (int ch = 0; ch < 4; ch++) {
      float v[9];
#pragma unroll
      for (int di = 0; di < 3; di++)
#pragma unroll
        for (int dj = 0; dj < 3; dj++) v[di * 3 + dj] = tile[ch][ty + di][tx + dj];
      const float* wc = pw + (c0 + ch) * 9;   // pw[(o*64 + c)*9 + d]
#pragma unroll
      for (int o = 0; o < NOFF; o++) {
        const float* w9 = wc + o * (CH * 9);
#pragma unroll
        for (int d = 0; d < 9; d++) acc[o] += w9[d] * v[d];
      }
    }
    __syncthreads();
  }
  int i = i0 + ty, j = j0 + tx;
#pragma unroll
  for (int o = 0; o < NOFF; o++)
    offset[((b * NOFF + o) * HH + i) * WW + j] = acc[o];
}

// ---------------------------------------------------------------------------
// Kernel 2: pre-arrange conv_w into MFMA A-fragment order, bf16.
// wfrag[s][mt][lane][j]: A[m=oc][k=t], oc = mt*16 + (lane&15),
// t = s*32 + (lane>>4)*8 + j; t = k*64 + c -> element = cw[(oc*64+c)*9 + k].
// ---------------------------------------------------------------------------
__global__ void prep_wfrag(const float* __restrict__ cw, __bf16* __restrict__ wf) {
  int gid = blockIdx.x * 256 + threadIdx.x;   // 144*256 == 18*4*64*8
  int j    = gid & 7;
  int lane = (gid >> 3) & 63;
  int mt   = (gid >> 9) & 3;
  int s    = gid >> 11;
  int oc = mt * 16 + (lane & 15);
  int t  = s * 32 + (lane >> 4) * 8 + j;
  int k = t >> 6, c = t & 63;
  wf[gid] = (__bf16)cw[(oc * CH + c) * 9 + k];
}

// ---------------------------------------------------------------------------
// Kernel 3: fused bilinear deform gather (f32 -> bf16 LDS) + MFMA GEMM.
// Block = (b, i, 32-wide j strip).  D[oc][pix] via mfma_f32_16x16x32_bf16.
// ---------------------------------------------------------------------------
__global__ __launch_bounds__(256) void deform_gemm(
    const float* __restrict__ x0, const float* __restrict__ offset,
    const __bf16* __restrict__ wf, float* __restrict__ out) {
  __shared__ __align__(16) __bf16 xoff[PIX * XS];   // 37376 B

  int blk = blockIdx.x;              // ((b*128 + i)*4 + jh)
  int jh = blk & 3;
  int i  = (blk >> 2) & 127;
  int b  = blk >> 9;
  int j0 = jh << 5;
  int tid = threadIdx.x;

  // ---- Phase A: bilinear gather into LDS (bf16, k-major: t = k*64 + c) ----
  {
    int p  = tid & 31;
    int cg = tid >> 5;               // 8 groups x 8 channels
    int j  = j0 + p;
    const float* xb = x0 + (b * CH + cg * 8) * HW;
    const float* offp = offset + (b * NOFF * HH + i) * WW + j;
#pragma unroll 1
    for (int k = 0; k < 9; k++) {
      float ox = offp[k * HW];
      float oy = offp[(k + 9) * HW];
      float pxr = (float)(i + k / 3) + ox;     // p = p0 + p_n + off (1-indexed, padded)
      float pyr = (float)(j + k % 3) + oy;
      float fx = floorf(pxr), fy = floorf(pyr);
      float qltx = fminf(fmaxf(fx, 0.f), 129.f);
      float qlty = fminf(fmaxf(fy, 0.f), 129.f);
      float qrbx = fminf(fmaxf(fx + 1.f, 0.f), 129.f);
      float qrby = fminf(fmaxf(fy + 1.f, 0.f), 129.f);
      float px = fminf(fmaxf(pxr, 0.f), 129.f);
      float py = fminf(fmaxf(pyr, 0.f), 129.f);
      float glt = (1.f + qltx - px) * (1.f + qlty - py);
      float grb = (1.f - qrbx + px) * (1.f - qrby + py);
      float glb = (1.f + qltx - px) * (1.f - qrby + py);
      float grt = (1.f - qrbx + px) * (1.f + qlty - py);
      int ltx = (int)qltx - 1, lty = (int)qlty - 1;
      int rbx = (int)qrbx - 1, rby = (int)qrby - 1;
      bool vlx = (unsigned)ltx < 128u, vly = (unsigned)lty < 128u;
      bool vrx = (unsigned)rbx < 128u, vry = (unsigned)rby < 128u;
      int o_lt = ltx * WW + lty, o_rb = rbx * WW + rby;
      int o_lb = ltx * WW + rby, o_rt = rbx * WW + lty;
      bf16x8 v;
#pragma unroll
      for (int cc = 0; cc < 8; cc++) {
        const float* xc = xb + cc * HW;
        float vlt = (vlx && vly) ? xc[o_lt] : 0.f;
        float vrb = (vrx && vry) ? xc[o_rb] : 0.f;
        float vlb = (vlx && vry) ? xc[o_lb] : 0.f;
        float vrt = (vrx && vly) ? xc[o_rt] : 0.f;
        v[cc] = (__bf16)(glt * vlt + grb * vrb + glb * vlb + grt * vrt);
      }
      *(bf16x8*)&xoff[p * XS + k * 64 + cg * 8] = v;
    }
  }
  __syncthreads();

  // ---- Phase B: D[oc][pix] = sum_t A[oc][t] * B[t][pix], K = 576 ----
  {
    int lane = tid & 63;
    int w    = tid >> 6;
    int ptile = w & 1;               // which 16 pixels
    int mt0   = (w >> 1) * 2;        // which pair of oc-tiles
    f32x4 acc0 = {0.f, 0.f, 0.f, 0.f};
    f32x4 acc1 = {0.f, 0.f, 0.f, 0.f};
    const __bf16* xrow = &xoff[(ptile * 16 + (lane & 15)) * XS + (lane >> 4) * 8];
    const bf16x8* wfv = (const bf16x8*)wf;
#pragma unroll 3
    for (int s = 0; s < 18; s++) {
      bf16x8 bfrag = *(const bf16x8*)(xrow + s * 32);
      bf16x8 a0 = wfv[(s * 4 + mt0) * 64 + lane];
      bf16x8 a1 = wfv[(s * 4 + mt0 + 1) * 64 + lane];
      acc0 = __builtin_amdgcn_mfma_f32_16x16x32_bf16(a0, bfrag, acc0, 0, 0, 0);
      acc1 = __builtin_amdgcn_mfma_f32_16x16x32_bf16(a1, bfrag, acc1, 0, 0, 0);
    }
    int col = lane & 15, quad = lane >> 4;
    int pix = ptile * 16 + col;
    int j = j0 + pix;
#pragma unroll
    for (int r = 0; r < 4; r++) {
      int oc0 = mt0 * 16 + quad * 4 + r;
      int oc1 = (mt0 + 1) * 16 + quad * 4 + r;
      out[((b * OC + oc0) * HH + i) * WW + j] = acc0[r];
      out[((b * OC + oc1) * HH + i) * WW + j] = acc1[r];
    }
  }
}

// ---------------------------------------------------------------------------
extern "C" void kernel_launch(void* const* d_in, const int* in_sizes, int n_in,
                              void* d_out, int out_size, void* d_ws, size_t ws_size,
                              hipStream_t stream) {
  const float* x0 = (const float*)d_in[0];
  const float* x1 = (const float*)d_in[1];
  const float* pw = (const float*)d_in[2];
  const float* pb = (const float*)d_in[3];
  const float* cw = (const float*)d_in[4];
  float* out = (float*)d_out;

  float*  offset = (float*)d_ws;                      // 4*18*128*128 f32 = 4718592 B
  __bf16* wfrag  = (__bf16*)((char*)d_ws + 4718592);  // 36864 bf16 = 73728 B

  offset_conv<<<dim3(BATCH * 64), dim3(256), 0, stream>>>(x1, pw, pb, offset);
  prep_wfrag<<<dim3(144), dim3(256), 0, stream>>>(cw, wfrag);
  deform_gemm<<<dim3(BATCH * 128 * 4), dim3(256), 0, stream>>>(x0, offset, wfrag, out);
}

// Round 3
// 189.210 us; speedup vs baseline: 2.9441x; 1.6283x over previous
//
#include <hip/hip_runtime.h>

// Problem constants: b=4, c=64, h=w=128, ks=3, N=9, offset ch=18, oc=64.
#define BATCH 4
#define CH    64
#define HH    128
#define WW    128
#define HW    (HH*WW)          // 16384
#define NOFF  18               // 2*N
#define OC    64
#define PIX   32               // pixels per block (one row strip)
#define XS    584              // LDS row stride in bf16 (576 + 8, 16B aligned)
#define OSTR  33               // offs LDS row stride (floats) — conflict-free

typedef __attribute__((ext_vector_type(8))) __bf16 bf16x8;
typedef __attribute__((ext_vector_type(4))) float f32x4;

// ---------------------------------------------------------------------------
// Prep: conv_w -> wfrag (A-frag, M=64, 36864 elems) and p_w -> pwfrag
// (A-frag, M=32 padded from 18, 18432 elems). t = k*64 + c (k-major).
// ---------------------------------------------------------------------------
__global__ void prep_frags(const float* __restrict__ cw, const float* __restrict__ pw,
                           __bf16* __restrict__ wf, __bf16* __restrict__ pf) {
  int gid = blockIdx.x * 256 + threadIdx.x;   // 216*256 = 55296 = 36864 + 18432
  if (gid < 36864) {
    int j = gid & 7, lane = (gid >> 3) & 63, mt = (gid >> 9) & 3, s = gid >> 11;
    int oc = mt * 16 + (lane & 15);
    int t = s * 32 + (lane >> 4) * 8 + j;
    int k = t >> 6, c = t & 63;
    wf[gid] = (__bf16)cw[(oc * CH + c) * 9 + k];
  } else {
    int g = gid - 36864;                      // ((s*2+mt)*64 + lane)*8 + j
    int j = g & 7, lane = (g >> 3) & 63, mt = (g >> 9) & 1, s = g >> 10;
    int o = mt * 16 + (lane & 15);
    int t = s * 32 + (lane >> 4) * 8 + j;
    int k = t >> 6, c = t & 63;
    pf[g] = (o < NOFF) ? (__bf16)pw[(o * CH + c) * 9 + k] : (__bf16)0.f;
  }
}

// ---------------------------------------------------------------------------
// Fused: x1 im2col staging -> offset MFMA -> bilinear gather -> main MFMA.
// Block = (b, i, 32-wide j strip), 256 threads (4 waves).
// ---------------------------------------------------------------------------
__global__ __launch_bounds__(256, 4) void deform_fused(
    const float* __restrict__ x0, const float* __restrict__ x1,
    const __bf16* __restrict__ pf, const float* __restrict__ pb,
    const __bf16* __restrict__ wf, float* __restrict__ out) {
  __shared__ __align__(16) __bf16 xoff[PIX * XS];   // 37376 B (reused twice)
  __shared__ float offs[NOFF * OSTR];               // 2376 B

  int blk = blockIdx.x;              // ((b*128 + i)*4 + jh)
  int jh = blk & 3;
  int i  = (blk >> 2) & 127;
  int b  = blk >> 9;
  int j0 = jh << 5;
  int tid = threadIdx.x;
  int p  = tid & 31;                 // pixel in strip
  int cg = tid >> 5;                 // channel group (8 ch each)

  // ---- Phase 0: stage x1 im2col patch as bf16, k-major: t = k*64 + c ----
  {
    const float* xb = x1 + (b * CH + cg * 8) * HW;
    int j = j0 + p;
#pragma unroll
    for (int k = 0; k < 9; k++) {
      int gi = i + k / 3 - 1;
      int gj = j + k % 3 - 1;
      bf16x8 v;
      if ((unsigned)gi < 128u && (unsigned)gj < 128u) {
        const float* sp = xb + gi * WW + gj;
#pragma unroll
        for (int cc = 0; cc < 8; cc++) v[cc] = (__bf16)sp[cc * HW];
      } else {
#pragma unroll
        for (int cc = 0; cc < 8; cc++) v[cc] = (__bf16)0.f;
      }
      *(bf16x8*)&xoff[p * XS + k * 64 + cg * 8] = v;
    }
  }
  __syncthreads();

  // ---- Phase 1: offset GEMM, D[o][pix], M=32 (18 used), K=576 ----
  {
    int lane = tid & 63, w = tid >> 6;
    int ptile = w & 1;               // 16-pixel half
    int mt    = w >> 1;              // M-tile (o 0-15 / 16-31)
    f32x4 acc = {0.f, 0.f, 0.f, 0.f};
    const __bf16* xrow = &xoff[(ptile * 16 + (lane & 15)) * XS + (lane >> 4) * 8];
    const bf16x8* pfv = (const bf16x8*)pf;
#pragma unroll 3
    for (int s = 0; s < 18; s++) {
      bf16x8 bfrag = *(const bf16x8*)(xrow + s * 32);
      bf16x8 afrag = pfv[(s * 2 + mt) * 64 + lane];
      acc = __builtin_amdgcn_mfma_f32_16x16x32_bf16(afrag, bfrag, acc, 0, 0, 0);
    }
    int col = lane & 15, quad = lane >> 4;
    int pix = ptile * 16 + col;
#pragma unroll
    for (int r = 0; r < 4; r++) {
      int o = mt * 16 + quad * 4 + r;
      if (o < NOFF) offs[o * OSTR + pix] = acc[r] + pb[o];
    }
  }
  __syncthreads();

  // ---- Phase 2: bilinear gather into xoff (bf16, k-major), offsets from LDS ----
  {
    const float* xb = x0 + (b * CH + cg * 8) * HW;
    int j = j0 + p;
#pragma unroll 1
    for (int k = 0; k < 9; k++) {
      float ox = offs[k * OSTR + p];
      float oy = offs[(k + 9) * OSTR + p];
      float pxr = (float)(i + k / 3) + ox;   // p = p0 + p_n + off (1-indexed, padded)
      float pyr = (float)(j + k % 3) + oy;
      float fx = floorf(pxr), fy = floorf(pyr);
      float qltx = fminf(fmaxf(fx, 0.f), 129.f);
      float qlty = fminf(fmaxf(fy, 0.f), 129.f);
      float qrbx = fminf(fmaxf(fx + 1.f, 0.f), 129.f);
      float qrby = fminf(fmaxf(fy + 1.f, 0.f), 129.f);
      float px = fminf(fmaxf(pxr, 0.f), 129.f);
      float py = fminf(fmaxf(pyr, 0.f), 129.f);
      float glt = (1.f + qltx - px) * (1.f + qlty - py);
      float grb = (1.f - qrbx + px) * (1.f - qrby + py);
      float glb = (1.f + qltx - px) * (1.f - qrby + py);
      float grt = (1.f - qrbx + px) * (1.f + qlty - py);
      int ltx = (int)qltx - 1, lty = (int)qlty - 1;
      int rbx = (int)qrbx - 1, rby = (int)qrby - 1;
      bool vlx = (unsigned)ltx < 128u, vly = (unsigned)lty < 128u;
      bool vrx = (unsigned)rbx < 128u, vry = (unsigned)rby < 128u;
      int o_lt = ltx * WW + lty, o_rb = rbx * WW + rby;
      int o_lb = ltx * WW + rby, o_rt = rbx * WW + lty;
      bf16x8 v;
#pragma unroll
      for (int cc = 0; cc < 8; cc++) {
        const float* xc = xb + cc * HW;
        float vlt = (vlx && vly) ? xc[o_lt] : 0.f;
        float vrb = (vrx && vry) ? xc[o_rb] : 0.f;
        float vlb = (vlx && vry) ? xc[o_lb] : 0.f;
        float vrt = (vrx && vly) ? xc[o_rt] : 0.f;
        v[cc] = (__bf16)(glt * vlt + grb * vrb + glb * vlb + grt * vrt);
      }
      *(bf16x8*)&xoff[p * XS + k * 64 + cg * 8] = v;
    }
  }
  __syncthreads();

  // ---- Phase 3: main GEMM, D[oc][pix], M=64, K=576 ----
  {
    int lane = tid & 63, w = tid >> 6;
    int ptile = w & 1;
    int mt0   = (w >> 1) * 2;
    f32x4 acc0 = {0.f, 0.f, 0.f, 0.f};
    f32x4 acc1 = {0.f, 0.f, 0.f, 0.f};
    const __bf16* xrow = &xoff[(ptile * 16 + (lane & 15)) * XS + (lane >> 4) * 8];
    const bf16x8* wfv = (const bf16x8*)wf;
#pragma unroll 3
    for (int s = 0; s < 18; s++) {
      bf16x8 bfrag = *(const bf16x8*)(xrow + s * 32);
      bf16x8 a0 = wfv[(s * 4 + mt0) * 64 + lane];
      bf16x8 a1 = wfv[(s * 4 + mt0 + 1) * 64 + lane];
      acc0 = __builtin_amdgcn_mfma_f32_16x16x32_bf16(a0, bfrag, acc0, 0, 0, 0);
      acc1 = __builtin_amdgcn_mfma_f32_16x16x32_bf16(a1, bfrag, acc1, 0, 0, 0);
    }
    int col = lane & 15, quad = lane >> 4;
    int pix = ptile * 16 + col;
    int j = j0 + pix;
#pragma unroll
    for (int r = 0; r < 4; r++) {
      int oc0 = mt0 * 16 + quad * 4 + r;
      int oc1 = (mt0 + 1) * 16 + quad * 4 + r;
      out[((b * OC + oc0) * HH + i) * WW + j] = acc0[r];
      out[((b * OC + oc1) * HH + i) * WW + j] = acc1[r];
    }
  }
}

// ---------------------------------------------------------------------------
extern "C" void kernel_launch(void* const* d_in, const int* in_sizes, int n_in,
                              void* d_out, int out_size, void* d_ws, size_t ws_size,
                              hipStream_t stream) {
  const float* x0 = (const float*)d_in[0];
  const float* x1 = (const float*)d_in[1];
  const float* pw = (const float*)d_in[2];
  const float* pb = (const float*)d_in[3];
  const float* cw = (const float*)d_in[4];
  float* out = (float*)d_out;

  __bf16* wfrag  = (__bf16*)d_ws;                      // 36864 bf16 = 73728 B
  __bf16* pwfrag = (__bf16*)((char*)d_ws + 73728);     // 18432 bf16 = 36864 B

  prep_frags<<<dim3(216), dim3(256), 0, stream>>>(cw, pw, wfrag, pwfrag);
  deform_fused<<<dim3(BATCH * 128 * 4), dim3(256), 0, stream>>>(
      x0, x1, pwfrag, pb, wfrag, out);
}

// Round 4
// 186.117 us; speedup vs baseline: 2.9931x; 1.0166x over previous
//
#include <hip/hip_runtime.h>

// Problem constants: b=4, c=64, h=w=128, ks=3, N=9, offset ch=18, oc=64.
#define BATCH 4
#define CH    64
#define HH    128
#define WW    128
#define HW    (HH*WW)          // 16384
#define NOFF  18               // 2*N
#define OC    64
#define PIX   16               // pixels per block (one row strip)
#define XS    584              // LDS row stride in bf16 (576+8): dword stride 292 ≡ 4 mod 32 -> conflict-free b128
#define OSTR  17               // offs LDS row stride (floats)

typedef __attribute__((ext_vector_type(8))) __bf16 bf16x8;
typedef __attribute__((ext_vector_type(4))) __bf16 bf16x4;
typedef __attribute__((ext_vector_type(4))) float f32x4;

// ---------------------------------------------------------------------------
// Prep: conv_w -> wfrag (A-frag, M=64) and p_w -> pwfrag (A-frag, M=32 padded
// from 18). GEMM K-index t = k*64 + c (k-major).
// ---------------------------------------------------------------------------
__global__ void prep_frags(const float* __restrict__ cw, const float* __restrict__ pw,
                           __bf16* __restrict__ wf, __bf16* __restrict__ pf) {
  int gid = blockIdx.x * 256 + threadIdx.x;   // 216*256 = 55296 = 36864 + 18432
  if (gid < 36864) {
    int j = gid & 7, lane = (gid >> 3) & 63, mt = (gid >> 9) & 3, s = gid >> 11;
    int oc = mt * 16 + (lane & 15);
    int t = s * 32 + (lane >> 4) * 8 + j;
    int k = t >> 6, c = t & 63;
    wf[gid] = (__bf16)cw[(oc * CH + c) * 9 + k];
  } else {
    int g = gid - 36864;                      // ((s*2+mt)*64 + lane)*8 + j
    int j = g & 7, lane = (g >> 3) & 63, mt = (g >> 9) & 1, s = g >> 10;
    int o = mt * 16 + (lane & 15);
    int t = s * 32 + (lane >> 4) * 8 + j;
    int k = t >> 6, c = t & 63;
    pf[g] = (o < NOFF) ? (__bf16)pw[(o * CH + c) * 9 + k] : (__bf16)0.f;
  }
}

// ---------------------------------------------------------------------------
// Fused: x1 im2col staging -> offset MFMA -> bilinear gather -> main MFMA.
// Block = 16-pixel row strip, 256 threads (4 waves), 8 blocks/CU (LDS 19.9KB).
// XCD band swizzle: XCD k owns 64 contiguous (b,i) rows -> ~4.3MB L2 set.
// ---------------------------------------------------------------------------
__global__ __launch_bounds__(256, 8) void deform_fused(
    const float* __restrict__ x0, const float* __restrict__ x1,
    const __bf16* __restrict__ pf, const float* __restrict__ pb,
    const __bf16* __restrict__ wf, float* __restrict__ out) {
  __shared__ __align__(16) __bf16 xoff[PIX * XS];   // 18688 B (reused twice)
  __shared__ float offs[NOFF * OSTR];               // 1224 B

  // swizzle: consecutive blockIdx round-robin over 8 XCDs; give XCD its band
  int blk = blockIdx.x;              // 4096 blocks
  int xcd   = blk & 7;
  int local = blk >> 3;              // 0..511
  int strip = xcd * 512 + local;     // per-XCD contiguous (b,i) band
  int jh = strip & 7;
  int i  = (strip >> 3) & 127;
  int b  = strip >> 10;
  int j0 = jh << 4;
  int tid = threadIdx.x;
  int p  = tid & 15;                 // pixel in strip
  int cg = tid >> 4;                 // channel group (4 ch each, 16 groups)

  // ---- Phase 0: stage x1 im2col patch as bf16, k-major: t = k*64 + c ----
  {
    const float* xb = x1 + (b * CH + cg * 4) * HW;
    int j = j0 + p;
#pragma unroll
    for (int k = 0; k < 9; k++) {
      int gi = i + k / 3 - 1;
      int gj = j + k % 3 - 1;
      bf16x4 v;
      if ((unsigned)gi < 128u && (unsigned)gj < 128u) {
        const float* sp = xb + gi * WW + gj;
#pragma unroll
        for (int cc = 0; cc < 4; cc++) v[cc] = (__bf16)sp[cc * HW];
      } else {
#pragma unroll
        for (int cc = 0; cc < 4; cc++) v[cc] = (__bf16)0.f;
      }
      *(bf16x4*)&xoff[p * XS + k * 64 + cg * 4] = v;
    }
  }
  __syncthreads();

  // ---- Phase 1: offset GEMM, D[o][pix], M=32 (18 used), K=576, waves 0-1 ----
  {
    int lane = tid & 63, w = tid >> 6;
    if (w < 2) {
      int mt = w;                    // M-tile (o 0-15 / 16-31)
      f32x4 acc = {0.f, 0.f, 0.f, 0.f};
      const __bf16* xrow = &xoff[(lane & 15) * XS + (lane >> 4) * 8];
      const bf16x8* pfv = (const bf16x8*)pf;
#pragma unroll 3
      for (int s = 0; s < 18; s++) {
        bf16x8 bfrag = *(const bf16x8*)(xrow + s * 32);
        bf16x8 afrag = pfv[(s * 2 + mt) * 64 + lane];
        acc = __builtin_amdgcn_mfma_f32_16x16x32_bf16(afrag, bfrag, acc, 0, 0, 0);
      }
      int col = lane & 15, quad = lane >> 4;
#pragma unroll
      for (int r = 0; r < 4; r++) {
        int o = mt * 16 + quad * 4 + r;
        if (o < NOFF) offs[o * OSTR + col] = acc[r] + pb[o];
      }
    }
  }
  __syncthreads();

  // ---- Phase 2: bilinear gather into xoff (bf16, k-major), offsets from LDS ----
  {
    const float* xb = x0 + (b * CH + cg * 4) * HW;
    int j = j0 + p;
#pragma unroll 1
    for (int k = 0; k < 9; k++) {
      float ox = offs[k * OSTR + p];
      float oy = offs[(k + 9) * OSTR + p];
      float pxr = (float)(i + k / 3) + ox;   // p = p0 + p_n + off (1-indexed, padded)
      float pyr = (float)(j + k % 3) + oy;
      float fx = floorf(pxr), fy = floorf(pyr);
      float qltx = fminf(fmaxf(fx, 0.f), 129.f);
      float qlty = fminf(fmaxf(fy, 0.f), 129.f);
      float qrbx = fminf(fmaxf(fx + 1.f, 0.f), 129.f);
      float qrby = fminf(fmaxf(fy + 1.f, 0.f), 129.f);
      float px = fminf(fmaxf(pxr, 0.f), 129.f);
      float py = fminf(fmaxf(pyr, 0.f), 129.f);
      float glt = (1.f + qltx - px) * (1.f + qlty - py);
      float grb = (1.f - qrbx + px) * (1.f - qrby + py);
      float glb = (1.f + qltx - px) * (1.f - qrby + py);
      float grt = (1.f - qrbx + px) * (1.f + qlty - py);
      int ltx = (int)qltx - 1, lty = (int)qlty - 1;
      int rbx = (int)qrbx - 1, rby = (int)qrby - 1;
      bool vlx = (unsigned)ltx < 128u, vly = (unsigned)lty < 128u;
      bool vrx = (unsigned)rbx < 128u, vry = (unsigned)rby < 128u;
      int o_lt = ltx * WW + lty, o_rb = rbx * WW + rby;
      int o_lb = ltx * WW + rby, o_rt = rbx * WW + lty;
      bf16x4 v;
#pragma unroll
      for (int cc = 0; cc < 4; cc++) {
        const float* xc = xb + cc * HW;
        float vlt = (vlx && vly) ? xc[o_lt] : 0.f;
        float vrb = (vrx && vry) ? xc[o_rb] : 0.f;
        float vlb = (vlx && vry) ? xc[o_lb] : 0.f;
        float vrt = (vrx && vly) ? xc[o_rt] : 0.f;
        v[cc] = (__bf16)(glt * vlt + grb * vrb + glb * vlb + grt * vrt);
      }
      *(bf16x4*)&xoff[p * XS + k * 64 + cg * 4] = v;
    }
  }
  __syncthreads();

  // ---- Phase 3: main GEMM, D[oc][pix], M=64, K=576, one M-tile per wave ----
  {
    int lane = tid & 63, w = tid >> 6;
    int mt = w;                      // 16 oc per wave
    f32x4 acc = {0.f, 0.f, 0.f, 0.f};
    const __bf16* xrow = &xoff[(lane & 15) * XS + (lane >> 4) * 8];
    const bf16x8* wfv = (const bf16x8*)wf;
#pragma unroll 3
    for (int s = 0; s < 18; s++) {
      bf16x8 bfrag = *(const bf16x8*)(xrow + s * 32);
      bf16x8 afrag = wfv[(s * 4 + mt) * 64 + lane];
      acc = __builtin_amdgcn_mfma_f32_16x16x32_bf16(afrag, bfrag, acc, 0, 0, 0);
    }
    int col = lane & 15, quad = lane >> 4;
    int j = j0 + col;
#pragma unroll
    for (int r = 0; r < 4; r++) {
      int oc = mt * 16 + quad * 4 + r;
      out[((b * OC + oc) * HH + i) * WW + j] = acc[r];
    }
  }
}

// ---------------------------------------------------------------------------
extern "C" void kernel_launch(void* const* d_in, const int* in_sizes, int n_in,
                              void* d_out, int out_size, void* d_ws, size_t ws_size,
                              hipStream_t stream) {
  const float* x0 = (const float*)d_in[0];
  const float* x1 = (const float*)d_in[1];
  const float* pw = (const float*)d_in[2];
  const float* pb = (const float*)d_in[3];
  const float* cw = (const float*)d_in[4];
  float* out = (float*)d_out;

  __bf16* wfrag  = (__bf16*)d_ws;                      // 36864 bf16 = 73728 B
  __bf16* pwfrag = (__bf16*)((char*)d_ws + 73728);     // 18432 bf16 = 36864 B

  prep_frags<<<dim3(216), dim3(256), 0, stream>>>(cw, pw, wfrag, pwfrag);
  deform_fused<<<dim3(BATCH * 128 * 8), dim3(256), 0, stream>>>(
      x0, x1, pwfrag, pb, wfrag, out);
}

// Round 5
// 182.441 us; speedup vs baseline: 3.0534x; 1.0201x over previous
//
#include <hip/hip_runtime.h>

// Problem constants: b=4, c=64, h=w=128, ks=3, N=9, offset ch=18, oc=64.
#define BATCH 4
#define CH    64
#define HH    128
#define WW    128
#define HW    (HH*WW)          // 16384
#define HP    130              // padded H/W
#define NOFF  18               // 2*N
#define OC    64
#define PIX   16               // pixels per block (one row strip)
#define XS    584              // LDS row stride in bf16 (576+8), keeps b128 reads 16B-aligned
#define OSTR  17               // offs LDS row stride (floats)

typedef __attribute__((ext_vector_type(8))) __bf16 bf16x8;
typedef __attribute__((ext_vector_type(4))) __bf16 bf16x4;
typedef __attribute__((ext_vector_type(4))) float f32x4;

// ws layout (bytes):
//   wfrag  @ 0        : 36864 bf16 = 73728
//   pwfrag @ 73728    : 18432 bf16 = 36864
//   x0t    @ 110592   : 4*130*130*64 bf16 = 8652800   (padded NHWC, zero ring)
//   x1t    @ 8763392  : same                           total ~17.4 MB
#define WF_OFF  0
#define PF_OFF  73728
#define X0T_OFF 110592
#define X1T_OFF 8763392

// ---------------------------------------------------------------------------
// prep_all: blocks 0..1039 transpose NCHW f32 -> padded NHWC bf16 (x0t/x1t,
// zero ring baked in); blocks 1040..1255 build MFMA A-fragments.
// ---------------------------------------------------------------------------
__global__ void prep_all(const float* __restrict__ x0, const float* __restrict__ x1,
                         const float* __restrict__ cw, const float* __restrict__ pw,
                         __bf16* __restrict__ x0t, __bf16* __restrict__ x1t,
                         __bf16* __restrict__ wf, __bf16* __restrict__ pf) {
  int blk = blockIdx.x;
  int tid = threadIdx.x;
  if (blk < 1040) {
    // transpose one (input, b, padded-row ip)
    __shared__ float tile[64 * 132];
    int which = blk / 520;
    int rem   = blk % 520;
    int b  = rem / HP;
    int ip = rem % HP;
    const float* src = which ? x1 : x0;
    __bf16* dst = which ? x1t : x0t;
    __bf16* drow = dst + (size_t)(b * HP + ip) * HP * CH;
    if (ip == 0 || ip == HP - 1) {
      // zero row: 130*64 bf16 = 16640 B = 1040 x 16B
      int4 z = {0, 0, 0, 0};
      for (int e = tid; e < 1040; e += 256) *(int4*)((char*)drow + e * 16) = z;
    } else {
      int i = ip - 1;
      // read 64c x 128j as float4 (2048 float4, 8 per thread), coalesced
#pragma unroll
      for (int it = 0; it < 8; it++) {
        int idx = it * 256 + tid;          // 0..2047
        int c = idx >> 5, j4 = (idx & 31) << 2;
        float4 v = *(const float4*)(src + (size_t)(b * CH + c) * HW + i * WW + j4);
        *(float4*)&tile[c * 132 + j4] = v;
      }
      __syncthreads();
      // write interior columns jo = 1..128 (j = jo-1), 32 channels per thread
      int j  = tid >> 1;
      int c0 = (tid & 1) * 32;
      __bf16* dp = drow + (j + 1) * CH + c0;
#pragma unroll
      for (int g8 = 0; g8 < 4; g8++) {
        bf16x8 v;
#pragma unroll
        for (int cc = 0; cc < 8; cc++) v[cc] = (__bf16)tile[(c0 + g8 * 8 + cc) * 132 + j];
        *(bf16x8*)(dp + g8 * 8) = v;
      }
      // ring columns jo=0 and jo=129: 2 x 64 ch = 256 B
      if (tid < 16) {
        int col = tid >> 3;                 // 0 or 1
        int off = (tid & 7) * 8;
        __bf16* zp = drow + (col ? (HP - 1) * CH : 0) + off;
        int4 z = {0, 0, 0, 0};
        *(int4*)zp = z;
      }
    }
  } else {
    // fragment prep; GEMM K-index t = k*64 + c (k-major)
    int gid = (blk - 1040) * 256 + tid;     // 216*256 = 55296 = 36864 + 18432
    if (gid < 36864) {
      int j = gid & 7, lane = (gid >> 3) & 63, mt = (gid >> 9) & 3, s = gid >> 11;
      int oc = mt * 16 + (lane & 15);
      int t = s * 32 + (lane >> 4) * 8 + j;
      int k = t >> 6, c = t & 63;
      wf[gid] = (__bf16)cw[(oc * CH + c) * 9 + k];
    } else {
      int g = gid - 36864;                  // ((s*2+mt)*64 + lane)*8 + j
      int j = g & 7, lane = (g >> 3) & 63, mt = (g >> 9) & 1, s = g >> 10;
      int o = mt * 16 + (lane & 15);
      int t = s * 32 + (lane >> 4) * 8 + j;
      int k = t >> 6, c = t & 63;
      pf[g] = (o < NOFF) ? (__bf16)pw[(o * CH + c) * 9 + k] : (__bf16)0.f;
    }
  }
}

// ---------------------------------------------------------------------------
// Fused: x1t im2col staging -> offset MFMA -> bilinear gather (NHWC bf16,
// no bounds checks) -> main MFMA. 16-pixel strip, 4 waves, 8 blocks/CU.
// XCD band swizzle: XCD k owns 64 contiguous (b,i) rows.
// ---------------------------------------------------------------------------
__global__ __launch_bounds__(256, 8) void deform_fused(
    const __bf16* __restrict__ x0t, const __bf16* __restrict__ x1t,
    const __bf16* __restrict__ pf, const float* __restrict__ pb,
    const __bf16* __restrict__ wf, float* __restrict__ out) {
  __shared__ __align__(16) __bf16 xoff[PIX * XS];   // 18688 B (reused twice)
  __shared__ float offs[NOFF * OSTR];               // 1224 B

  int blk = blockIdx.x;              // 4096 blocks
  int xcd   = blk & 7;
  int local = blk >> 3;              // 0..511
  int strip = xcd * 512 + local;     // per-XCD contiguous (b,i) band
  int jh = strip & 7;
  int i  = (strip >> 3) & 127;
  int b  = strip >> 10;
  int j0 = jh << 4;
  int tid = threadIdx.x;
  int p  = tid & 15;                 // pixel in strip
  int cg = tid >> 4;                 // channel group (4 ch each, 16 groups)
  int j  = j0 + p;

  // ---- Phase 0: stage x1t im2col patch (already bf16), k-major t = k*64+c ----
  {
    const __bf16* xb = x1t + ((size_t)b * HP * HP) * CH + cg * 4;
#pragma unroll
    for (int k = 0; k < 9; k++) {
      int gi = i + k / 3;            // padded row index
      int gj = j + k % 3;
      bf16x4 v = *(const bf16x4*)(xb + (gi * HP + gj) * CH);
      *(bf16x4*)&xoff[p * XS + k * 64 + cg * 4] = v;
    }
  }
  __syncthreads();

  // ---- Phase 1: offset GEMM, D[o][pix], M=32 (18 used), K=576, waves 0-1 ----
  {
    int lane = tid & 63, w = tid >> 6;
    if (w < 2) {
      int mt = w;
      f32x4 acc = {0.f, 0.f, 0.f, 0.f};
      const __bf16* xrow = &xoff[(lane & 15) * XS + (lane >> 4) * 8];
      const bf16x8* pfv = (const bf16x8*)pf;
#pragma unroll 3
      for (int s = 0; s < 18; s++) {
        bf16x8 bfrag = *(const bf16x8*)(xrow + s * 32);
        bf16x8 afrag = pfv[(s * 2 + mt) * 64 + lane];
        acc = __builtin_amdgcn_mfma_f32_16x16x32_bf16(afrag, bfrag, acc, 0, 0, 0);
      }
      int col = lane & 15, quad = lane >> 4;
#pragma unroll
      for (int r = 0; r < 4; r++) {
        int o = mt * 16 + quad * 4 + r;
        if (o < NOFF) offs[o * OSTR + col] = acc[r] + pb[o];
      }
    }
  }
  __syncthreads();

  // ---- Phase 2: bilinear gather from padded NHWC bf16 (no validity logic) ----
  {
    const __bf16* xb = x0t + ((size_t)b * HP * HP) * CH + cg * 4;
#pragma unroll 3
    for (int k = 0; k < 9; k++) {
      float ox = offs[k * OSTR + p];
      float oy = offs[(k + 9) * OSTR + p];
      float pxr = (float)(i + k / 3) + ox;   // padded coords (p0 + p_n + off)
      float pyr = (float)(j + k % 3) + oy;
      float fx = floorf(pxr), fy = floorf(pyr);
      float qltx = fminf(fmaxf(fx, 0.f), 129.f);
      float qlty = fminf(fmaxf(fy, 0.f), 129.f);
      float qrbx = fminf(fmaxf(fx + 1.f, 0.f), 129.f);
      float qrby = fminf(fmaxf(fy + 1.f, 0.f), 129.f);
      float px = fminf(fmaxf(pxr, 0.f), 129.f);
      float py = fminf(fmaxf(pyr, 0.f), 129.f);
      float glt = (1.f + qltx - px) * (1.f + qlty - py);
      float grb = (1.f - qrbx + px) * (1.f - qrby + py);
      float glb = (1.f + qltx - px) * (1.f - qrby + py);
      float grt = (1.f - qrbx + px) * (1.f + qlty - py);
      int iltx = (int)qltx, ilty = (int)qlty;
      int irbx = (int)qrbx, irby = (int)qrby;
      const __bf16* r_lt = xb + (iltx * HP + ilty) * CH;
      const __bf16* r_rb = xb + (irbx * HP + irby) * CH;
      const __bf16* r_lb = xb + (iltx * HP + irby) * CH;
      const __bf16* r_rt = xb + (irbx * HP + ilty) * CH;
      bf16x4 vlt = *(const bf16x4*)r_lt;
      bf16x4 vrb = *(const bf16x4*)r_rb;
      bf16x4 vlb = *(const bf16x4*)r_lb;
      bf16x4 vrt = *(const bf16x4*)r_rt;
      bf16x4 v;
#pragma unroll
      for (int cc = 0; cc < 4; cc++) {
        v[cc] = (__bf16)(glt * (float)vlt[cc] + grb * (float)vrb[cc] +
                         glb * (float)vlb[cc] + grt * (float)vrt[cc]);
      }
      *(bf16x4*)&xoff[p * XS + k * 64 + cg * 4] = v;
    }
  }
  __syncthreads();

  // ---- Phase 3: main GEMM, D[oc][pix], M=64, K=576, one M-tile per wave ----
  {
    int lane = tid & 63, w = tid >> 6;
    int mt = w;                      // 16 oc per wave
    f32x4 acc = {0.f, 0.f, 0.f, 0.f};
    const __bf16* xrow = &xoff[(lane & 15) * XS + (lane >> 4) * 8];
    const bf16x8* wfv = (const bf16x8*)wf;
#pragma unroll 3
    for (int s = 0; s < 18; s++) {
      bf16x8 bfrag = *(const bf16x8*)(xrow + s * 32);
      bf16x8 afrag = wfv[(s * 4 + mt) * 64 + lane];
      acc = __builtin_amdgcn_mfma_f32_16x16x32_bf16(afrag, bfrag, acc, 0, 0, 0);
    }
    int col = lane & 15, quad = lane >> 4;
    int jo = j0 + col;
#pragma unroll
    for (int r = 0; r < 4; r++) {
      int oc = mt * 16 + quad * 4 + r;
      out[((b * OC + oc) * HH + i) * WW + jo] = acc[r];
    }
  }
}

// ---------------------------------------------------------------------------
extern "C" void kernel_launch(void* const* d_in, const int* in_sizes, int n_in,
                              void* d_out, int out_size, void* d_ws, size_t ws_size,
                              hipStream_t stream) {
  const float* x0 = (const float*)d_in[0];
  const float* x1 = (const float*)d_in[1];
  const float* pw = (const float*)d_in[2];
  const float* pb = (const float*)d_in[3];
  const float* cw = (const float*)d_in[4];
  float* out = (float*)d_out;

  __bf16* wfrag  = (__bf16*)((char*)d_ws + WF_OFF);
  __bf16* pwfrag = (__bf16*)((char*)d_ws + PF_OFF);
  __bf16* x0t    = (__bf16*)((char*)d_ws + X0T_OFF);
  __bf16* x1t    = (__bf16*)((char*)d_ws + X1T_OFF);

  prep_all<<<dim3(1256), dim3(256), 0, stream>>>(x0, x1, cw, pw, x0t, x1t, wfrag, pwfrag);
  deform_fused<<<dim3(BATCH * 128 * 8), dim3(256), 0, stream>>>(
      x0t, x1t, pwfrag, pb, wfrag, out);
}

// Round 6
// 174.445 us; speedup vs baseline: 3.1933x; 1.0458x over previous
//
#include <hip/hip_runtime.h>

// Problem: b=4, c=64, h=w=128, ks=3, N=9, offset ch=18, oc=64. Padded HP=130.
#define BATCH 4
#define CH    64
#define HH    128
#define WW    128
#define HW    (HH*WW)
#define HP    130
#define NOFF  18
#define OC    64

typedef _Float16 half8 __attribute__((ext_vector_type(8)));
typedef _Float16 half2t __attribute__((ext_vector_type(2)));
typedef float f32x4 __attribute__((ext_vector_type(4)));

// ws layout (bytes):
//   wf   @ 0        : 36864 f16 = 73728      (main-conv A-frags)
//   pf   @ 73728    : 18432 f16 = 36864      (offset-conv A-frags, M padded to 32)
//   x0t  @ 110592   : 4*130*130*64 f16 = 8652800   (padded NHWC, zero ring)
//   x1t  @ 8763392  : 8652800
//   recs @ 17416192 : 65536*9*16 = 9437184   -> total 26853376 B
#define WF_OFF  0
#define PF_OFF  73728
#define X0T_OFF 110592
#define X1T_OFF 8763392
#define REC_OFF 17416192

// ---------------------------------------------------------------------------
// Kernel A: blocks 0..2047: transpose half-rows NCHW f32 -> padded NHWC f16;
// blocks 2048..2063: zero top/bottom ring rows; 2064..2279: A-fragments.
// ---------------------------------------------------------------------------
__global__ __launch_bounds__(256) void prep_all(
    const float* __restrict__ x0, const float* __restrict__ x1,
    const float* __restrict__ cw, const float* __restrict__ pw,
    _Float16* __restrict__ x0t, _Float16* __restrict__ x1t,
    _Float16* __restrict__ wf, _Float16* __restrict__ pf) {
  int blk = blockIdx.x, tid = threadIdx.x;
  if (blk < 2048) {
    __shared__ float tile[64 * 66];
    int jh = blk & 1, i = (blk >> 1) & 127, b = (blk >> 8) & 3, which = blk >> 10;
    const float* src = which ? x1 : x0;
    _Float16* dst = which ? x1t : x0t;
#pragma unroll
    for (int it = 0; it < 4; it++) {
      int idx = it * 256 + tid;            // 1024 float4 = 64c x 64j
      int c = idx >> 4, j4 = (idx & 15) << 2;
      float4 v = *(const float4*)(src + (size_t)(b * CH + c) * HW + i * WW + jh * 64 + j4);
      *(float4*)&tile[c * 66 + j4] = v;
    }
    __syncthreads();
    int jl = tid >> 2, cq = (tid & 3) << 4;   // 64 j x 4 groups of 16 ch
    _Float16* dp = dst + ((size_t)(b * HP + i + 1) * HP + (jh * 64 + jl + 1)) * CH + cq;
#pragma unroll
    for (int h = 0; h < 2; h++) {
      half8 v;
#pragma unroll
      for (int cc = 0; cc < 8; cc++) v[cc] = (_Float16)tile[(cq + h * 8 + cc) * 66 + jl];
      *(half8*)(dp + h * 8) = v;
    }
    if (tid < 8) {                          // ring column jo=0 (jh0) / jo=129 (jh1)
      int jo = jh ? (HP - 1) : 0;
      _Float16* zp = dst + ((size_t)(b * HP + i + 1) * HP + jo) * CH + tid * 8;
      int4 z = {0, 0, 0, 0};
      *(int4*)zp = z;
    }
  } else if (blk < 2064) {
    int z = blk - 2048;                     // 2 which x 4 b x 2 rows
    int which = z >> 3, b = (z >> 1) & 3, top = z & 1;
    _Float16* dst = (which ? x1t : x0t) + ((size_t)(b * HP + top * (HP - 1)) * HP) * CH;
    int4 zz = {0, 0, 0, 0};
    for (int e = tid; e < 1040; e += 256) *(int4*)((char*)dst + e * 16) = zz;
  } else {
    // A-fragments; GEMM K-index t = k*64 + c (k-major)
    int gid = (blk - 2064) * 256 + tid;     // 216*256 = 55296 = 36864 + 18432
    if (gid < 36864) {
      int j = gid & 7, lane = (gid >> 3) & 63, mt = (gid >> 9) & 3, s = gid >> 11;
      int oc = mt * 16 + (lane & 15);
      int t = s * 32 + (lane >> 4) * 8 + j;
      int k = t >> 6, c = t & 63;
      wf[gid] = (_Float16)cw[(oc * CH + c) * 9 + k];
    } else {
      int g = gid - 36864;
      int j = g & 7, lane = (g >> 3) & 63, mt = (g >> 9) & 1, s = g >> 10;
      int o = mt * 16 + (lane & 15);
      int t = s * 32 + (lane >> 4) * 8 + j;
      int k = t >> 6, c = t & 63;
      pf[g] = (o < NOFF) ? (_Float16)pw[(o * CH + c) * 9 + k] : (_Float16)0.f;
    }
  }
}

// ---------------------------------------------------------------------------
// Kernel B: offset GEMM (M=32 padded from 18, K=576) with B-frags loaded
// straight from x1t (no staging), then per-(pixel,k) record generation:
// rec = { ltx|lty<<16, rbx|rby<<16, half2(g_lt,g_rb), half2(g_lb,g_rt) }.
// Block = (b, i, 64-j half): 4 waves x 16 pixels. Grid 1024.
// ---------------------------------------------------------------------------
__global__ __launch_bounds__(256) void offset_recs(
    const _Float16* __restrict__ x1t, const _Float16* __restrict__ pf,
    const float* __restrict__ pb, int4* __restrict__ recs) {
  __shared__ float offs_lds[64 * 20];
  int blk = blockIdx.x;
  int jh2 = blk & 1, i = (blk >> 1) & 127, b = blk >> 8;
  int j0 = jh2 * 64;
  int tid = threadIdx.x, lane = tid & 63, nt = tid >> 6;
  int p = lane & 15, q = lane >> 4;
  int j = j0 + nt * 16 + p;
  const _Float16* x1b = x1t + (size_t)b * HP * HP * CH;
  const half8* pfv = (const half8*)pf;
  f32x4 acc0 = {0.f, 0.f, 0.f, 0.f}, acc1 = {0.f, 0.f, 0.f, 0.f};
#pragma unroll 3
  for (int s = 0; s < 18; s++) {
    int u = 4 * s + q, k = u >> 3, c0 = (u & 7) << 3;
    int ki = (k * 86) >> 8, kj = k - ki * 3;          // k/3, k%3 for k<9
    half8 bfrag = *(const half8*)(x1b + ((i + ki) * HP + (j + kj)) * CH + c0);
    acc0 = __builtin_amdgcn_mfma_f32_16x16x32_f16(pfv[(s * 2 + 0) * 64 + lane], bfrag, acc0, 0, 0, 0);
    acc1 = __builtin_amdgcn_mfma_f32_16x16x32_f16(pfv[(s * 2 + 1) * 64 + lane], bfrag, acc1, 0, 0, 0);
  }
  int col = lane & 15, quad = lane >> 4;
  int px = nt * 16 + col;
#pragma unroll
  for (int r = 0; r < 4; r++) {
    int o = quad * 4 + r;
    offs_lds[px * 20 + o] = acc0[r] + pb[o];
    int o2 = 16 + o;
    if (o2 < NOFF) offs_lds[px * 20 + o2] = acc1[r] + pb[o2];
  }
  __syncthreads();
  int px2 = tid >> 2, kg = tid & 3;       // 64 pixels x 4 k-groups
  int jj = j0 + px2;
#pragma unroll
  for (int t = 0; t < 3; t++) {
    int k = kg + t * 4;                   // kg0:{0,4,8} kg1:{1,5} kg2:{2,6} kg3:{3,7}
    if (k <= 8) {
      float ox = offs_lds[px2 * 20 + k], oy = offs_lds[px2 * 20 + k + 9];
      int ki = (k * 86) >> 8, kj = k - ki * 3;
      float pxr = (float)(i + ki) + ox;   // padded coords: p = p0 + p_n + off
      float pyr = (float)(jj + kj) + oy;
      float fx = floorf(pxr), fy = floorf(pyr);
      float qltx = fminf(fmaxf(fx, 0.f), 129.f);
      float qlty = fminf(fmaxf(fy, 0.f), 129.f);
      float qrbx = fminf(fmaxf(fx + 1.f, 0.f), 129.f);
      float qrby = fminf(fmaxf(fy + 1.f, 0.f), 129.f);
      float pxc = fminf(fmaxf(pxr, 0.f), 129.f);
      float pyc = fminf(fmaxf(pyr, 0.f), 129.f);
      float glt = (1.f + qltx - pxc) * (1.f + qlty - pyc);
      float grb = (1.f - qrbx + pxc) * (1.f - qrby + pyc);
      float glb = (1.f + qltx - pxc) * (1.f - qrby + pyc);
      float grt = (1.f - qrbx + pxc) * (1.f + qlty - pyc);
      int4 rec;
      rec.x = (int)qltx | ((int)qlty << 16);
      rec.y = (int)qrbx | ((int)qrby << 16);
      half2t gA = {(_Float16)glt, (_Float16)grb};
      half2t gB = {(_Float16)glb, (_Float16)grt};
      rec.z = __builtin_bit_cast(int, gA);
      rec.w = __builtin_bit_cast(int, gB);
      recs[(size_t)((b * HH + i) * WW + jj) * 9 + k] = rec;
    }
  }
}

// ---------------------------------------------------------------------------
// Kernel C: barrier-free, LDS-free gather+GEMM. Wave = 16 pixels x 32 oc.
// Per m (=sample k): 1 record (broadcast over quads), 8 corner f16x8 loads,
// packed-f16 interp -> two B-frags in registers -> 4 MFMAs. 8192 waves.
// XCD band swizzle: each XCD owns 64 contiguous (b,i) rows.
// ---------------------------------------------------------------------------
__global__ __launch_bounds__(256, 4) void deform_mfma(
    const _Float16* __restrict__ x0t, const int4* __restrict__ recs,
    const _Float16* __restrict__ wf, float* __restrict__ out) {
  int xcd = blockIdx.x & 7, local = blockIdx.x >> 3;
  int ublk = xcd * 256 + local;
  int tid = threadIdx.x, w = tid >> 6, lane = tid & 63;
  int u = ublk * 4 + w;                    // 0..8191
  int mh = u & 1, jq = (u >> 1) & 7, i = (u >> 4) & 127, b = u >> 11;
  int p = lane & 15, q = lane >> 4;
  int j = jq * 16 + p;
  const int4* recp = recs + (size_t)((b * HH + i) * WW + j) * 9;
  const _Float16* x0b = x0t + (size_t)b * HP * HP * CH;
  const half8* wfv = (const half8*)wf;
  int mt0 = mh * 2;
  int c0 = q * 8;
  f32x4 acc0 = {0.f, 0.f, 0.f, 0.f}, acc1 = {0.f, 0.f, 0.f, 0.f};
#pragma unroll 3
  for (int m = 0; m < 9; m++) {
    int4 rec = recp[m];
    int ltx = rec.x & 0xffff, lty = (int)((unsigned)rec.x >> 16);
    int rbx = rec.y & 0xffff, rby = (int)((unsigned)rec.y >> 16);
    int rl = ltx * HP, rr = rbx * HP;
    const _Float16* plt = x0b + (rl + lty) * CH + c0;
    const _Float16* prb = x0b + (rr + rby) * CH + c0;
    const _Float16* plb = x0b + (rl + rby) * CH + c0;
    const _Float16* prt = x0b + (rr + lty) * CH + c0;
    half2t gA = __builtin_bit_cast(half2t, rec.z);
    half2t gB = __builtin_bit_cast(half2t, rec.w);
    _Float16 glt = gA.x, grb = gA.y, glb = gB.x, grt = gB.y;
    // B-frag for s=2m (t = m*64 + q*8 + j) and s=2m+1 (+32 channels)
    half8 f0 = (*(const half8*)plt) * glt + (*(const half8*)prb) * grb +
               (*(const half8*)plb) * glb + (*(const half8*)prt) * grt;
    half8 f1 = (*(const half8*)(plt + 32)) * glt + (*(const half8*)(prb + 32)) * grb +
               (*(const half8*)(plb + 32)) * glb + (*(const half8*)(prt + 32)) * grt;
    int s0 = 2 * m;
    acc0 = __builtin_amdgcn_mfma_f32_16x16x32_f16(wfv[(s0 * 4 + mt0) * 64 + lane], f0, acc0, 0, 0, 0);
    acc1 = __builtin_amdgcn_mfma_f32_16x16x32_f16(wfv[(s0 * 4 + mt0 + 1) * 64 + lane], f0, acc1, 0, 0, 0);
    acc0 = __builtin_amdgcn_mfma_f32_16x16x32_f16(wfv[((s0 + 1) * 4 + mt0) * 64 + lane], f1, acc0, 0, 0, 0);
    acc1 = __builtin_amdgcn_mfma_f32_16x16x32_f16(wfv[((s0 + 1) * 4 + mt0 + 1) * 64 + lane], f1, acc1, 0, 0, 0);
  }
  int col = lane & 15, quad = lane >> 4;
  int jo = jq * 16 + col;
#pragma unroll
  for (int r = 0; r < 4; r++) {
    int oc0 = mt0 * 16 + quad * 4 + r;
    int oc1 = (mt0 + 1) * 16 + quad * 4 + r;
    out[((b * OC + oc0) * HH + i) * WW + jo] = acc0[r];
    out[((b * OC + oc1) * HH + i) * WW + jo] = acc1[r];
  }
}

// ---------------------------------------------------------------------------
extern "C" void kernel_launch(void* const* d_in, const int* in_sizes, int n_in,
                              void* d_out, int out_size, void* d_ws, size_t ws_size,
                              hipStream_t stream) {
  const float* x0 = (const float*)d_in[0];
  const float* x1 = (const float*)d_in[1];
  const float* pw = (const float*)d_in[2];
  const float* pb = (const float*)d_in[3];
  const float* cw = (const float*)d_in[4];
  float* out = (float*)d_out;

  _Float16* wfrag  = (_Float16*)((char*)d_ws + WF_OFF);
  _Float16* pwfrag = (_Float16*)((char*)d_ws + PF_OFF);
  _Float16* x0t    = (_Float16*)((char*)d_ws + X0T_OFF);
  _Float16* x1t    = (_Float16*)((char*)d_ws + X1T_OFF);
  int4*     recs   = (int4*)((char*)d_ws + REC_OFF);

  prep_all<<<dim3(2280), dim3(256), 0, stream>>>(x0, x1, cw, pw, x0t, x1t, wfrag, pwfrag);
  offset_recs<<<dim3(1024), dim3(256), 0, stream>>>(x1t, pwfrag, pb, recs);
  deform_mfma<<<dim3(2048), dim3(256), 0, stream>>>(x0t, recs, wfrag, out);
}

// Round 7
// 147.810 us; speedup vs baseline: 3.7687x; 1.1802x over previous
//
#include <hip/hip_runtime.h>

// Problem: b=4, c=64, h=w=128, ks=3, N=9, offset ch=18, oc=64. Padded HP=130.
#define BATCH 4
#define CH    64
#define HH    128
#define WW    128
#define HW    (HH*WW)
#define HP    130
#define NOFF  18
#define OC    64

typedef _Float16 half8 __attribute__((ext_vector_type(8)));
typedef _Float16 half2t __attribute__((ext_vector_type(2)));
typedef float f32x4 __attribute__((ext_vector_type(4)));

// ws layout (bytes):
//   wf   @ 0        : 36864 f16 (main A-frags)      pf @ 73728: 18432 f16
//   x0t  @ 110592   : 4*130*130*64 f16 (padded NHWC, zero ring)
//   x1t  @ 8763392  : same
//   recs @ 17416192 : 65536*9*16 B                  total 26853376 B
#define WF_OFF  0
#define PF_OFF  73728
#define X0T_OFF 110592
#define X1T_OFF 8763392
#define REC_OFF 17416192

// ---------------------------------------------------------------------------
// Kernel A: blocks 0..2047 transpose half-rows NCHW f32 -> padded NHWC f16;
// 2048..2063 zero ring rows; 2064..2279 A-fragments (k-major t = k*64+c).
// ---------------------------------------------------------------------------
__global__ __launch_bounds__(256) void prep_all(
    const float* __restrict__ x0, const float* __restrict__ x1,
    const float* __restrict__ cw, const float* __restrict__ pw,
    _Float16* __restrict__ x0t, _Float16* __restrict__ x1t,
    _Float16* __restrict__ wf, _Float16* __restrict__ pf) {
  int blk = blockIdx.x, tid = threadIdx.x;
  if (blk < 2048) {
    __shared__ float tile[64 * 66];
    int jh = blk & 1, i = (blk >> 1) & 127, b = (blk >> 8) & 3, which = blk >> 10;
    const float* src = which ? x1 : x0;
    _Float16* dst = which ? x1t : x0t;
#pragma unroll
    for (int it = 0; it < 4; it++) {
      int idx = it * 256 + tid;            // 1024 float4 = 64c x 64j
      int c = idx >> 4, j4 = (idx & 15) << 2;
      float4 v = *(const float4*)(src + (size_t)(b * CH + c) * HW + i * WW + jh * 64 + j4);
      *(float4*)&tile[c * 66 + j4] = v;
    }
    __syncthreads();
    int jl = tid >> 2, cq = (tid & 3) << 4;
    _Float16* dp = dst + ((size_t)(b * HP + i + 1) * HP + (jh * 64 + jl + 1)) * CH + cq;
#pragma unroll
    for (int h = 0; h < 2; h++) {
      half8 v;
#pragma unroll
      for (int cc = 0; cc < 8; cc++) v[cc] = (_Float16)tile[(cq + h * 8 + cc) * 66 + jl];
      *(half8*)(dp + h * 8) = v;
    }
    if (tid < 8) {                          // ring column jo=0 (jh0) / jo=129 (jh1)
      int jo = jh ? (HP - 1) : 0;
      _Float16* zp = dst + ((size_t)(b * HP + i + 1) * HP + jo) * CH + tid * 8;
      int4 z = {0, 0, 0, 0};
      *(int4*)zp = z;
    }
  } else if (blk < 2064) {
    int z = blk - 2048;
    int which = z >> 3, b = (z >> 1) & 3, top = z & 1;
    _Float16* dst = (which ? x1t : x0t) + ((size_t)(b * HP + top * (HP - 1)) * HP) * CH;
    int4 zz = {0, 0, 0, 0};
    for (int e = tid; e < 1040; e += 256) *(int4*)((char*)dst + e * 16) = zz;
  } else {
    int gid = (blk - 2064) * 256 + tid;     // 216*256 = 36864 + 18432
    if (gid < 36864) {
      int j = gid & 7, lane = (gid >> 3) & 63, mt = (gid >> 9) & 3, s = gid >> 11;
      int oc = mt * 16 + (lane & 15);
      int t = s * 32 + (lane >> 4) * 8 + j;
      int k = t >> 6, c = t & 63;
      wf[gid] = (_Float16)cw[(oc * CH + c) * 9 + k];
    } else {
      int g = gid - 36864;
      int j = g & 7, lane = (g >> 3) & 63, mt = (g >> 9) & 1, s = g >> 10;
      int o = mt * 16 + (lane & 15);
      int t = s * 32 + (lane >> 4) * 8 + j;
      int k = t >> 6, c = t & 63;
      pf[g] = (o < NOFF) ? (_Float16)pw[(o * CH + c) * 9 + k] : (_Float16)0.f;
    }
  }
}

// ---------------------------------------------------------------------------
// Kernel B: offset GEMM (M=32 padded from 18, K=576). x1t rows staged into
// LDS coalesced (stride 72 f16 -> 2-way banks = free), B-frags via ds_read.
// Then per-(pixel,k) record: {ltx|lty<<16, rbx|rby<<16, h2(glt,grb), h2(glb,grt)}.
// Block = (b,i,64-j half): 4 waves x 16 px. Grid 1024, 4 blocks/CU.
// ---------------------------------------------------------------------------
__global__ __launch_bounds__(256, 4) void offset_recs(
    const _Float16* __restrict__ x1t, const _Float16* __restrict__ pf,
    const float* __restrict__ pb, int4* __restrict__ recs) {
  __shared__ _Float16 x1s[3 * 66 * 72];   // 28512 B
  __shared__ float offs_lds[64 * 20];     // 5120 B
  int blk = blockIdx.x;
  int jh2 = blk & 1, i = (blk >> 1) & 127, b = blk >> 8;
  int j0 = jh2 * 64;
  int tid = threadIdx.x, lane = tid & 63, nt = tid >> 6;
  const _Float16* x1b = x1t + (size_t)b * HP * HP * CH;

  // stage rows i..i+2, cols j0..j0+65 (coalesced 1KB per wave-instr)
#pragma unroll
  for (int it = 0; it < 7; it++) {
    int tau = it * 256 + tid;
    if (tau < 1584) {
      int ki = tau / 528, r2 = tau - ki * 528;
      int col = r2 >> 3, cg = r2 & 7;
      half8 v = *(const half8*)(x1b + ((size_t)(i + ki) * HP + (j0 + col)) * CH + cg * 8);
      *(half8*)&x1s[(ki * 66 + col) * 72 + cg * 8] = v;
    }
  }
  __syncthreads();

  int p = lane & 15, q = lane >> 4;
  const half8* pfv = (const half8*)pf;
  f32x4 acc0 = {0.f, 0.f, 0.f, 0.f}, acc1 = {0.f, 0.f, 0.f, 0.f};
#pragma unroll 3
  for (int s = 0; s < 18; s++) {
    int u = 4 * s + q, k = u >> 3, c0 = (u & 7) << 3;   // t = s*32+q*8 -> (k,c)
    int ki = (k * 86) >> 8, kj = k - ki * 3;
    half8 bfrag = *(const half8*)&x1s[(ki * 66 + nt * 16 + p + kj) * 72 + c0];
    acc0 = __builtin_amdgcn_mfma_f32_16x16x32_f16(pfv[(s * 2 + 0) * 64 + lane], bfrag, acc0, 0, 0, 0);
    acc1 = __builtin_amdgcn_mfma_f32_16x16x32_f16(pfv[(s * 2 + 1) * 64 + lane], bfrag, acc1, 0, 0, 0);
  }
  int col = lane & 15, quad = lane >> 4;
  int px = nt * 16 + col;
#pragma unroll
  for (int r = 0; r < 4; r++) {
    int o = quad * 4 + r;
    offs_lds[px * 20 + o] = acc0[r] + pb[o];
    int o2 = 16 + o;
    if (o2 < NOFF) offs_lds[px * 20 + o2] = acc1[r] + pb[o2];
  }
  __syncthreads();

  int px2 = tid >> 2, kg = tid & 3;
  int jj = j0 + px2;
#pragma unroll
  for (int t = 0; t < 3; t++) {
    int k = kg + t * 4;
    if (k <= 8) {
      float ox = offs_lds[px2 * 20 + k], oy = offs_lds[px2 * 20 + k + 9];
      int ki = (k * 86) >> 8, kj = k - ki * 3;
      float pxr = (float)(i + ki) + ox;   // padded coords: p = p0 + p_n + off
      float pyr = (float)(jj + kj) + oy;
      float fx = floorf(pxr), fy = floorf(pyr);
      float qltx = fminf(fmaxf(fx, 0.f), 129.f);
      float qlty = fminf(fmaxf(fy, 0.f), 129.f);
      float qrbx = fminf(fmaxf(fx + 1.f, 0.f), 129.f);
      float qrby = fminf(fmaxf(fy + 1.f, 0.f), 129.f);
      float pxc = fminf(fmaxf(pxr, 0.f), 129.f);
      float pyc = fminf(fmaxf(pyr, 0.f), 129.f);
      float glt = (1.f + qltx - pxc) * (1.f + qlty - pyc);
      float grb = (1.f - qrbx + pxc) * (1.f - qrby + pyc);
      float glb = (1.f + qltx - pxc) * (1.f - qrby + pyc);
      float grt = (1.f - qrbx + pxc) * (1.f + qlty - pyc);
      int4 rec;
      rec.x = (int)qltx | ((int)qlty << 16);
      rec.y = (int)qrbx | ((int)qrby << 16);
      half2t gA = {(_Float16)glt, (_Float16)grb};
      half2t gB = {(_Float16)glb, (_Float16)grt};
      rec.z = __builtin_bit_cast(int, gA);
      rec.w = __builtin_bit_cast(int, gB);
      recs[(size_t)((b * HH + i) * WW + jj) * 9 + k] = rec;
    }
  }
}

// ---------------------------------------------------------------------------
// Kernel C: fused coalesced gather+GEMM. Block = 32 px, 256 thr, 4 blocks/CU.
// Phase A: tid = px*8+cg -> 8 lanes hold 8 contiguous channel-chunks of ONE
// pixel-corner row => corner loads are 8x128B segments per instruction (not
// 64 scattered lines). In-lane interp -> each lane's half8 IS one B-frag
// slot -> one ds_write_b128 (frag-ordered tile). Phase B: lane-indexed
// ds_read_b128 (conflict-free) + coalesced A-frags + MFMA.
// XCD band swizzle: each XCD owns 64 contiguous rows of one image.
// ---------------------------------------------------------------------------
__global__ __launch_bounds__(256, 4) void deform_fused(
    const _Float16* __restrict__ x0t, const int4* __restrict__ recs,
    const _Float16* __restrict__ wf, float* __restrict__ out) {
  __shared__ __align__(16) _Float16 btile[2 * 18 * 64 * 8];   // 36864 B

  int xcd = blockIdx.x & 7, local = blockIdx.x >> 3;
  int strip = xcd * 256 + local;            // 0..2047
  int jq2 = strip & 3, i = (strip >> 2) & 127, b = strip >> 9;
  int j0 = jq2 * 32;
  int tid = threadIdx.x;
  const _Float16* x0b = x0t + (size_t)b * HP * HP * CH;

  // ---- Phase A: coalesced gather + interp -> frag-ordered LDS ----
  {
    int cg = tid & 7, px = tid >> 3;        // 32 px x 8 channel-chunks
    int c0 = cg * 8;
    int nt = px >> 4, pxl = px & 15, kgq = cg & 3, sh = cg >> 2;
    const int4* recp = recs + (size_t)((b * HH + i) * WW + (j0 + px)) * 9;
    int4 rec[9];
#pragma unroll
    for (int k = 0; k < 9; k++) rec[k] = recp[k];   // prefetch all records
#pragma unroll 3
    for (int k = 0; k < 9; k++) {
      int ltx = rec[k].x & 0xffff, lty = (int)((unsigned)rec[k].x >> 16);
      int rbx = rec[k].y & 0xffff, rby = (int)((unsigned)rec[k].y >> 16);
      const _Float16* rowl = x0b + (size_t)ltx * (HP * CH) + c0;
      const _Float16* rowr = x0b + (size_t)rbx * (HP * CH) + c0;
      half8 vlt = *(const half8*)(rowl + lty * CH);
      half8 vlb = *(const half8*)(rowl + rby * CH);
      half8 vrb = *(const half8*)(rowr + rby * CH);
      half8 vrt = *(const half8*)(rowr + lty * CH);
      half2t gA = __builtin_bit_cast(half2t, rec[k].z);
      half2t gB = __builtin_bit_cast(half2t, rec[k].w);
      half8 f = vlt * gA.x + vrb * gA.y + vlb * gB.x + vrt * gB.y;
      int s = k * 2 + sh;                   // t = k*64 + c0 + j  ->  frag (s, kgq, pxl)
      *(half8*)&btile[(((nt * 18 + s) * 4 + kgq) * 16 + pxl) * 8] = f;
    }
  }
  __syncthreads();

  // ---- Phase B: D[oc][px], M=64, N=16/wave, K=576 ----
  {
    int lane = tid & 63, w = tid >> 6;
    int nt = w & 1, mt0 = (w >> 1) * 2;
    f32x4 acc0 = {0.f, 0.f, 0.f, 0.f}, acc1 = {0.f, 0.f, 0.f, 0.f};
    const half8* wfv = (const half8*)wf;
    const half8* bt = (const half8*)&btile[nt * (18 * 512)];
#pragma unroll 6
    for (int s = 0; s < 18; s++) {
      half8 bfrag = bt[s * 64 + lane];
      acc0 = __builtin_amdgcn_mfma_f32_16x16x32_f16(wfv[(s * 4 + mt0) * 64 + lane], bfrag, acc0, 0, 0, 0);
      acc1 = __builtin_amdgcn_mfma_f32_16x16x32_f16(wfv[(s * 4 + mt0 + 1) * 64 + lane], bfrag, acc1, 0, 0, 0);
    }
    int col = lane & 15, quad = lane >> 4;
    int jo = j0 + nt * 16 + col;
#pragma unroll
    for (int r = 0; r < 4; r++) {
      int oc0 = mt0 * 16 + quad * 4 + r;
      int oc1 = (mt0 + 1) * 16 + quad * 4 + r;
      out[((b * OC + oc0) * HH + i) * WW + jo] = acc0[r];
      out[((b * OC + oc1) * HH + i) * WW + jo] = acc1[r];
    }
  }
}

// ---------------------------------------------------------------------------
extern "C" void kernel_launch(void* const* d_in, const int* in_sizes, int n_in,
                              void* d_out, int out_size, void* d_ws, size_t ws_size,
                              hipStream_t stream) {
  const float* x0 = (const float*)d_in[0];
  const float* x1 = (const float*)d_in[1];
  const float* pw = (const float*)d_in[2];
  const float* pb = (const float*)d_in[3];
  const float* cw = (const float*)d_in[4];
  float* out = (float*)d_out;

  _Float16* wfrag  = (_Float16*)((char*)d_ws + WF_OFF);
  _Float16* pwfrag = (_Float16*)((char*)d_ws + PF_OFF);
  _Float16* x0t    = (_Float16*)((char*)d_ws + X0T_OFF);
  _Float16* x1t    = (_Float16*)((char*)d_ws + X1T_OFF);
  int4*     recs   = (int4*)((char*)d_ws + REC_OFF);

  prep_all<<<dim3(2280), dim3(256), 0, stream>>>(x0, x1, cw, pw, x0t, x1t, wfrag, pwfrag);
  offset_recs<<<dim3(1024), dim3(256), 0, stream>>>(x1t, pwfrag, pb, recs);
  deform_fused<<<dim3(2048), dim3(256), 0, stream>>>(x0t, recs, wfrag, out);
}

// Round 8
// 120.892 us; speedup vs baseline: 4.6079x; 1.2227x over previous
//
#include <hip/hip_runtime.h>

// Problem: b=4, c=64, h=w=128, ks=3, N=9, offset ch=18, oc=64. Padded HP=130.
#define BATCH 4
#define CH    64
#define HH    128
#define WW    128
#define HW    (HH*WW)
#define HP    130
#define NOFF  18
#define OC    64

typedef _Float16 half8 __attribute__((ext_vector_type(8)));
typedef _Float16 half2t __attribute__((ext_vector_type(2)));
typedef float f32x4 __attribute__((ext_vector_type(4)));

// ws layout (bytes):
//   wf   @ 0        : 36864 f16 (main A-frags)      pf @ 73728: 18432 f16
//   x0t  @ 110592   : 4*130*130*64 f16 (padded NHWC, zero ring)
//   x1t  @ 8763392  : same
//   recs @ 17416192 : 65536*9*16 B                  total 26853376 B
#define WF_OFF  0
#define PF_OFF  73728
#define X0T_OFF 110592
#define X1T_OFF 8763392
#define REC_OFF 17416192

// ---------------------------------------------------------------------------
// Kernel A: blocks 0..2047 transpose half-rows NCHW f32 -> padded NHWC f16;
// 2048..2063 zero ring rows; 2064..2279 A-fragments (k-major t = k*64+c).
// ---------------------------------------------------------------------------
__global__ __launch_bounds__(256) void prep_all(
    const float* __restrict__ x0, const float* __restrict__ x1,
    const float* __restrict__ cw, const float* __restrict__ pw,
    _Float16* __restrict__ x0t, _Float16* __restrict__ x1t,
    _Float16* __restrict__ wf, _Float16* __restrict__ pf) {
  int blk = blockIdx.x, tid = threadIdx.x;
  if (blk < 2048) {
    __shared__ float tile[64 * 66];
    int jh = blk & 1, i = (blk >> 1) & 127, b = (blk >> 8) & 3, which = blk >> 10;
    const float* src = which ? x1 : x0;
    _Float16* dst = which ? x1t : x0t;
#pragma unroll
    for (int it = 0; it < 4; it++) {
      int idx = it * 256 + tid;            // 1024 float4 = 64c x 64j
      int c = idx >> 4, j4 = (idx & 15) << 2;
      float4 v = *(const float4*)(src + (size_t)(b * CH + c) * HW + i * WW + jh * 64 + j4);
      *(float4*)&tile[c * 66 + j4] = v;
    }
    __syncthreads();
    int jl = tid >> 2, cq = (tid & 3) << 4;
    _Float16* dp = dst + ((size_t)(b * HP + i + 1) * HP + (jh * 64 + jl + 1)) * CH + cq;
#pragma unroll
    for (int h = 0; h < 2; h++) {
      half8 v;
#pragma unroll
      for (int cc = 0; cc < 8; cc++) v[cc] = (_Float16)tile[(cq + h * 8 + cc) * 66 + jl];
      *(half8*)(dp + h * 8) = v;
    }
    if (tid < 8) {                          // ring column jo=0 (jh0) / jo=129 (jh1)
      int jo = jh ? (HP - 1) : 0;
      _Float16* zp = dst + ((size_t)(b * HP + i + 1) * HP + jo) * CH + tid * 8;
      int4 z = {0, 0, 0, 0};
      *(int4*)zp = z;
    }
  } else if (blk < 2064) {
    int z = blk - 2048;
    int which = z >> 3, b = (z >> 1) & 3, top = z & 1;
    _Float16* dst = (which ? x1t : x0t) + ((size_t)(b * HP + top * (HP - 1)) * HP) * CH;
    int4 zz = {0, 0, 0, 0};
    for (int e = tid; e < 1040; e += 256) *(int4*)((char*)dst + e * 16) = zz;
  } else {
    int gid = (blk - 2064) * 256 + tid;     // 216*256 = 36864 + 18432
    if (gid < 36864) {
      int j = gid & 7, lane = (gid >> 3) & 63, mt = (gid >> 9) & 3, s = gid >> 11;
      int oc = mt * 16 + (lane & 15);
      int t = s * 32 + (lane >> 4) * 8 + j;
      int k = t >> 6, c = t & 63;
      wf[gid] = (_Float16)cw[(oc * CH + c) * 9 + k];
    } else {
      int g = gid - 36864;
      int j = g & 7, lane = (g >> 3) & 63, mt = (g >> 9) & 1, s = g >> 10;
      int o = mt * 16 + (lane & 15);
      int t = s * 32 + (lane >> 4) * 8 + j;
      int k = t >> 6, c = t & 63;
      pf[g] = (o < NOFF) ? (_Float16)pw[(o * CH + c) * 9 + k] : (_Float16)0.f;
    }
  }
}

// ---------------------------------------------------------------------------
// Kernel B: offset GEMM (M=32 padded from 18, K=576). x1t rows staged into
// LDS coalesced, B-frags via ds_read. Then per-(pixel,k) record:
// {ltx|lty<<16, rbx|rby<<16, h2(glt,grb), h2(glb,grt)}.
// Block = (b,i,64-j half): 4 waves x 16 px. Grid 1024, 4 blocks/CU.
// ---------------------------------------------------------------------------
__global__ __launch_bounds__(256, 4) void offset_recs(
    const _Float16* __restrict__ x1t, const _Float16* __restrict__ pf,
    const float* __restrict__ pb, int4* __restrict__ recs) {
  __shared__ _Float16 x1s[3 * 66 * 72];   // 28512 B
  __shared__ float offs_lds[64 * 20];     // 5120 B
  int blk = blockIdx.x;
  int jh2 = blk & 1, i = (blk >> 1) & 127, b = blk >> 8;
  int j0 = jh2 * 64;
  int tid = threadIdx.x, lane = tid & 63, nt = tid >> 6;
  const _Float16* x1b = x1t + (size_t)b * HP * HP * CH;

  // stage rows i..i+2, cols j0..j0+65 (coalesced 1KB per wave-instr)
#pragma unroll
  for (int it = 0; it < 7; it++) {
    int tau = it * 256 + tid;
    if (tau < 1584) {
      int ki = tau / 528, r2 = tau - ki * 528;
      int col = r2 >> 3, cg = r2 & 7;
      half8 v = *(const half8*)(x1b + ((size_t)(i + ki) * HP + (j0 + col)) * CH + cg * 8);
      *(half8*)&x1s[(ki * 66 + col) * 72 + cg * 8] = v;
    }
  }
  __syncthreads();

  int p = lane & 15, q = lane >> 4;
  const half8* pfv = (const half8*)pf;
  f32x4 acc0 = {0.f, 0.f, 0.f, 0.f}, acc1 = {0.f, 0.f, 0.f, 0.f};
#pragma unroll 3
  for (int s = 0; s < 18; s++) {
    int u = 4 * s + q, k = u >> 3, c0 = (u & 7) << 3;   // t = s*32+q*8 -> (k,c)
    int ki = (k * 86) >> 8, kj = k - ki * 3;
    half8 bfrag = *(const half8*)&x1s[(ki * 66 + nt * 16 + p + kj) * 72 + c0];
    acc0 = __builtin_amdgcn_mfma_f32_16x16x32_f16(pfv[(s * 2 + 0) * 64 + lane], bfrag, acc0, 0, 0, 0);
    acc1 = __builtin_amdgcn_mfma_f32_16x16x32_f16(pfv[(s * 2 + 1) * 64 + lane], bfrag, acc1, 0, 0, 0);
  }
  int col = lane & 15, quad = lane >> 4;
  int px = nt * 16 + col;
#pragma unroll
  for (int r = 0; r < 4; r++) {
    int o = quad * 4 + r;
    offs_lds[px * 20 + o] = acc0[r] + pb[o];
    int o2 = 16 + o;
    if (o2 < NOFF) offs_lds[px * 20 + o2] = acc1[r] + pb[o2];
  }
  __syncthreads();

  int px2 = tid >> 2, kg = tid & 3;
  int jj = j0 + px2;
#pragma unroll
  for (int t = 0; t < 3; t++) {
    int k = kg + t * 4;
    if (k <= 8) {
      float ox = offs_lds[px2 * 20 + k], oy = offs_lds[px2 * 20 + k + 9];
      int ki = (k * 86) >> 8, kj = k - ki * 3;
      float pxr = (float)(i + ki) + ox;   // padded coords: p = p0 + p_n + off
      float pyr = (float)(jj + kj) + oy;
      float fx = floorf(pxr), fy = floorf(pyr);
      float qltx = fminf(fmaxf(fx, 0.f), 129.f);
      float qlty = fminf(fmaxf(fy, 0.f), 129.f);
      float qrbx = fminf(fmaxf(fx + 1.f, 0.f), 129.f);
      float qrby = fminf(fmaxf(fy + 1.f, 0.f), 129.f);
      float pxc = fminf(fmaxf(pxr, 0.f), 129.f);
      float pyc = fminf(fmaxf(pyr, 0.f), 129.f);
      float glt = (1.f + qltx - pxc) * (1.f + qlty - pyc);
      float grb = (1.f - qrbx + pxc) * (1.f - qrby + pyc);
      float glb = (1.f + qltx - pxc) * (1.f - qrby + pyc);
      float grt = (1.f - qrbx + pxc) * (1.f + qlty - pyc);
      int4 rec;
      rec.x = (int)qltx | ((int)qlty << 16);
      rec.y = (int)qrbx | ((int)qrby << 16);
      half2t gA = {(_Float16)glt, (_Float16)grb};
      half2t gB = {(_Float16)glb, (_Float16)grt};
      rec.z = __builtin_bit_cast(int, gA);
      rec.w = __builtin_bit_cast(int, gB);
      recs[(size_t)((b * HH + i) * WW + jj) * 9 + k] = rec;
    }
  }
}

// ---------------------------------------------------------------------------
// Kernel C: fused coalesced gather+GEMM. Block = 32 px, 256 thr, 4 blocks/CU.
// Phase A: tid = px*8+cg -> 8 lanes hold 8 contiguous channel-chunks of ONE
// pixel-corner row => coalesced corner loads. In-lane interp -> each lane's
// half8 IS one B-frag slot -> one ds_write_b128. Phase B: lane-indexed
// ds_read_b128 + coalesced A-frags + MFMA.
// k-loop FULLY unrolled, rec loaded per iteration (NO array -> no scratch).
// ---------------------------------------------------------------------------
__global__ __launch_bounds__(256, 4) void deform_fused(
    const _Float16* __restrict__ x0t, const int4* __restrict__ recs,
    const _Float16* __restrict__ wf, float* __restrict__ out) {
  __shared__ __align__(16) _Float16 btile[2 * 18 * 64 * 8];   // 36864 B

  int xcd = blockIdx.x & 7, local = blockIdx.x >> 3;
  int strip = xcd * 256 + local;            // 0..2047
  int jq2 = strip & 3, i = (strip >> 2) & 127, b = strip >> 9;
  int j0 = jq2 * 32;
  int tid = threadIdx.x;
  const _Float16* x0b = x0t + (size_t)b * HP * HP * CH;

  // ---- Phase A: coalesced gather + interp -> frag-ordered LDS ----
  {
    int cg = tid & 7, px = tid >> 3;        // 32 px x 8 channel-chunks
    int c0 = cg * 8;
    int nt = px >> 4, pxl = px & 15, kgq = cg & 3, sh = cg >> 2;
    const int4* recp = recs + (size_t)((b * HH + i) * WW + (j0 + px)) * 9;
    _Float16* wslot = &btile[(((nt * 18) * 4 + kgq) * 16 + pxl) * 8];
#pragma unroll
    for (int k = 0; k < 9; k++) {
      int4 rec = recp[k];
      int ltx = rec.x & 0xffff, lty = (int)((unsigned)rec.x >> 16);
      int rbx = rec.y & 0xffff, rby = (int)((unsigned)rec.y >> 16);
      const _Float16* rowl = x0b + (size_t)ltx * (HP * CH) + c0;
      const _Float16* rowr = x0b + (size_t)rbx * (HP * CH) + c0;
      half8 vlt = *(const half8*)(rowl + lty * CH);
      half8 vlb = *(const half8*)(rowl + rby * CH);
      half8 vrb = *(const half8*)(rowr + rby * CH);
      half8 vrt = *(const half8*)(rowr + lty * CH);
      half2t gA = __builtin_bit_cast(half2t, rec.z);
      half2t gB = __builtin_bit_cast(half2t, rec.w);
      half8 f = vlt * gA.x + vrb * gA.y + vlb * gB.x + vrt * gB.y;
      int s = k * 2 + sh;                   // t = k*64 + c0 + j  ->  frag (s, kgq, pxl)
      *(half8*)(wslot + s * 512) = f;       // 512 halfs per s-step
    }
  }
  __syncthreads();

  // ---- Phase B: D[oc][px], M=64, N=16/wave, K=576 ----
  {
    int lane = tid & 63, w = tid >> 6;
    int nt = w & 1, mt0 = (w >> 1) * 2;
    f32x4 acc0 = {0.f, 0.f, 0.f, 0.f}, acc1 = {0.f, 0.f, 0.f, 0.f};
    const half8* wfv = (const half8*)wf;
    const half8* bt = (const half8*)&btile[nt * (18 * 512)];
#pragma unroll 6
    for (int s = 0; s < 18; s++) {
      half8 bfrag = bt[s * 64 + lane];
      acc0 = __builtin_amdgcn_mfma_f32_16x16x32_f16(wfv[(s * 4 + mt0) * 64 + lane], bfrag, acc0, 0, 0, 0);
      acc1 = __builtin_amdgcn_mfma_f32_16x16x32_f16(wfv[(s * 4 + mt0 + 1) * 64 + lane], bfrag, acc1, 0, 0, 0);
    }
    int col = lane & 15, quad = lane >> 4;
    int jo = j0 + nt * 16 + col;
#pragma unroll
    for (int r = 0; r < 4; r++) {
      int oc0 = mt0 * 16 + quad * 4 + r;
      int oc1 = (mt0 + 1) * 16 + quad * 4 + r;
      out[((b * OC + oc0) * HH + i) * WW + jo] = acc0[r];
      out[((b * OC + oc1) * HH + i) * WW + jo] = acc1[r];
    }
  }
}

// ---------------------------------------------------------------------------
extern "C" void kernel_launch(void* const* d_in, const int* in_sizes, int n_in,
                              void* d_out, int out_size, void* d_ws, size_t ws_size,
                              hipStream_t stream) {
  const float* x0 = (const float*)d_in[0];
  const float* x1 = (const float*)d_in[1];
  const float* pw = (const float*)d_in[2];
  const float* pb = (const float*)d_in[3];
  const float* cw = (const float*)d_in[4];
  float* out = (float*)d_out;

  _Float16* wfrag  = (_Float16*)((char*)d_ws + WF_OFF);
  _Float16* pwfrag = (_Float16*)((char*)d_ws + PF_OFF);
  _Float16* x0t    = (_Float16*)((char*)d_ws + X0T_OFF);
  _Float16* x1t    = (_Float16*)((char*)d_ws + X1T_OFF);
  int4*     recs   = (int4*)((char*)d_ws + REC_OFF);

  prep_all<<<dim3(2280), dim3(256), 0, stream>>>(x0, x1, cw, pw, x0t, x1t, wfrag, pwfrag);
  offset_recs<<<dim3(1024), dim3(256), 0, stream>>>(x1t, pwfrag, pb, recs);
  deform_fused<<<dim3(2048), dim3(256), 0, stream>>>(x0t, recs, wfrag, out);
}